// Round 4
// baseline (4564.206 us; speedup 1.0000x reference)
//
#include <hip/hip_runtime.h>
#include <hip/hip_bf16.h>

#define B_SZ 1024
#define H_DIM 1536
#define H3 (3*H_DIM)
#define LMAX 32
#define TEMP_INV 20.0f
#define GH_BLOCKS 192

typedef __attribute__((ext_vector_type(4))) float f32x4;
typedef __attribute__((ext_vector_type(8))) short short8;
typedef unsigned short u16;
typedef unsigned int u32;

__device__ __forceinline__ u16 f2bf(float f){
  union { float f; u32 u; } v; v.f = f;
  u32 r = (v.u + 0x7FFFu + ((v.u >> 16) & 1u)) >> 16;
  return (u16)r;
}
__device__ __forceinline__ u32 pack2(float lo, float hi){
  return (u32)f2bf(lo) | ((u32)f2bf(hi) << 16);
}
__device__ __forceinline__ float bf2f(u16 b){
  union { u32 u; float f; } v; v.u = ((u32)b) << 16; return v.f;
}
__device__ __forceinline__ float sigm(float x){ return 1.f / (1.f + __expf(-x)); }

__device__ __forceinline__ void gload_lds16(const void* g, void* l){
  __builtin_amdgcn_global_load_lds(
      (const __attribute__((address_space(1))) void*)g,
      (__attribute__((address_space(3))) void*)l, 16, 0, 0);
}

// ---------------- prep: weights/k -> bf16, h0 = bf16(q) ----------------
__global__ void prep_kernel(const float* __restrict__ wih, const float* __restrict__ whh,
                            const float* __restrict__ kemb, const float* __restrict__ qemb,
                            u16* __restrict__ wih_bf, u16* __restrict__ whh_bf,
                            u16* __restrict__ k_bf, u16* __restrict__ h0)
{
  size_t o = ((size_t)blockIdx.x * 256 + threadIdx.x) * 8;
  if (o < (size_t)H3 * H_DIM) {
    float4 a0 = *(const float4*)(wih + o), a1 = *(const float4*)(wih + o + 4);
    *(uint4*)(wih_bf + o) = make_uint4(pack2(a0.x,a0.y), pack2(a0.z,a0.w),
                                       pack2(a1.x,a1.y), pack2(a1.z,a1.w));
    float4 b0 = *(const float4*)(whh + o), b1 = *(const float4*)(whh + o + 4);
    *(uint4*)(whh_bf + o) = make_uint4(pack2(b0.x,b0.y), pack2(b0.z,b0.w),
                                       pack2(b1.x,b1.y), pack2(b1.z,b1.w));
  }
  if (o < (size_t)B_SZ * H_DIM) {
    float4 k0 = *(const float4*)(kemb + o), k1 = *(const float4*)(kemb + o + 4);
    *(uint4*)(k_bf + o) = make_uint4(pack2(k0.x,k0.y), pack2(k0.z,k0.w),
                                     pack2(k1.x,k1.y), pack2(k1.z,k1.w));
    float4 q0 = *(const float4*)(qemb + o), q1 = *(const float4*)(qemb + o + 4);
    *(uint4*)(h0 + o) = make_uint4(pack2(q0.x,q0.y), pack2(q0.z,q0.w),
                                   pack2(q1.x,q1.y), pack2(q1.z,q1.w));
  }
}

// ---------------- convert inpn f32 -> bf16 (zero-pad to Mpad) ----------------
__global__ void convx_kernel(const float* __restrict__ x, u16* __restrict__ x_bf, int total){
  size_t o = ((size_t)blockIdx.x * 256 + threadIdx.x) * 8;
  int row = (int)(o / H_DIM);
  uint4 v;
  if (row < total) {
    float4 a0 = *(const float4*)(x + o), a1 = *(const float4*)(x + o + 4);
    v = make_uint4(pack2(a0.x,a0.y), pack2(a0.z,a0.w), pack2(a1.x,a1.y), pack2(a1.z,a1.w));
  } else v = make_uint4(0,0,0,0);
  *(uint4*)(x_bf + o) = v;
}

// ---------------- offsets: exclusive cumsum of lens ----------------
__global__ void offsets_kernel(const int* __restrict__ lens, int* __restrict__ offsets){
  __shared__ int s[B_SZ];
  int i = threadIdx.x;
  int v = lens[i];
  s[i] = v; __syncthreads();
  for (int off = 1; off < B_SZ; off <<= 1){
    int t = (i >= off) ? s[i-off] : 0;
    __syncthreads();
    s[i] += t;
    __syncthreads();
  }
  offsets[i] = s[i] - v;
}

// ---------------- active-row lists per step ----------------
__global__ void lists_kernel(const int* __restrict__ lens, int* __restrict__ lists,
                             int* __restrict__ counts){
  int t = blockIdx.x;
  int i = threadIdx.x;
  __shared__ int s[B_SZ];
  int f = (lens[i] > t) ? 1 : 0;
  s[i] = f; __syncthreads();
  for (int off = 1; off < B_SZ; off <<= 1){
    int v = (i >= off) ? s[i-off] : 0;
    __syncthreads();
    s[i] += v;
    __syncthreads();
  }
  if (f) lists[t*B_SZ + s[i] - 1] = i;
  if (i == B_SZ-1) counts[t] = s[B_SZ-1];
}

// ---------------- GI = x_bf @ W_ih^T + b_ih  (128x128 tile, BK=64) ----------------
__global__ __launch_bounds__(256, 2) void gi_gemm_kernel(
    const u16* __restrict__ x_bf, const u16* __restrict__ wih_bf,
    const float* __restrict__ b_ih, u16* __restrict__ gi, int nblk_m)
{
  int nblk = nblk_m * 36;
  int id = blockIdx.x;
  int q8 = nblk >> 3, r8 = nblk & 7;
  int xcd = id & 7, off = id >> 3;
  int swz = (xcd < r8) ? (xcd * (q8 + 1) + off) : (r8 * (q8 + 1) + (xcd - r8) * q8 + off);
  int bx = swz / 36, by = swz % 36;

  __shared__ u16 lds[2 * 128 * 64];   // 32 KB: A then B
  char* ldsb = (char*)lds;
  int tid = threadIdx.x, wid = tid >> 6, lane = tid & 63;
  int wm = wid >> 1, wn = wid & 1;
  int lrow = lane & 15, lkh = lane >> 4;
  f32x4 acc[4][4] = {};

  for (int kt = 0; kt < 24; ++kt) {
    int k0 = kt * 64;
    #pragma unroll
    for (int it = 0; it < 8; ++it) {
      int cb = it * 256 + wid * 64;        // wave-uniform chunk base
      int c  = cb + lane;
      int isB = c >> 10;
      int cc  = c & 1023;
      int row = cc >> 3, slot = cc & 7;
      const u16* src = isB ? (wih_bf + (size_t)(by * 128 + row) * H_DIM)
                           : (x_bf  + (size_t)(bx * 128 + row) * H_DIM);
      src += k0 + ((slot ^ (row & 7)) << 3);
      gload_lds16(src, ldsb + (size_t)cb * 16);
    }
    __syncthreads();
    #pragma unroll
    for (int qq = 0; qq < 2; ++qq) {
      short8 a[4], b[4];
      int slot = qq * 4 + lkh;
      #pragma unroll
      for (int m = 0; m < 4; ++m) {
        int row = wm * 64 + m * 16 + lrow;
        a[m] = *(const short8*)(ldsb + row * 128 + ((slot ^ (row & 7)) << 4));
      }
      #pragma unroll
      for (int n = 0; n < 4; ++n) {
        int row = wn * 64 + n * 16 + lrow;
        b[n] = *(const short8*)(ldsb + 16384 + row * 128 + ((slot ^ (row & 7)) << 4));
      }
      #pragma unroll
      for (int m = 0; m < 4; ++m)
        #pragma unroll
        for (int n = 0; n < 4; ++n)
          acc[m][n] = __builtin_amdgcn_mfma_f32_16x16x32_bf16(a[m], b[n], acc[m][n], 0,0,0);
    }
    __syncthreads();
  }
  #pragma unroll
  for (int n = 0; n < 4; ++n) {
    int j = by * 128 + wn * 64 + n * 16 + lrow;
    float bias = b_ih[j];
    #pragma unroll
    for (int m = 0; m < 4; ++m)
      #pragma unroll
      for (int r4 = 0; r4 < 4; ++r4) {
        int rowg = bx * 128 + wm * 64 + m * 16 + lkh * 4 + r4;
        gi[(size_t)rowg * 4608 + j] = f2bf(acc[m][n][r4] + bias);
      }
  }
}

// ---------------- persistent GRU recurrence: all 32 steps, one dispatch ----
// 192 blocks (8 XCD x 3 ct x 8 bx), 512 thr, BM=128 BN=64 BK=64,
// double-buffered LDS, grid barrier between steps (device-scope atomics).
__global__ __launch_bounds__(512, 2) void gh_persist_kernel(
    u16* __restrict__ hb0, u16* __restrict__ hb1,
    const u16* __restrict__ whh_bf, const u16* __restrict__ gi,
    const float* __restrict__ b_hh,
    const int* __restrict__ offsets, const int* __restrict__ lists,
    const int* __restrict__ counts, int* __restrict__ bar)
{
  int bid = blockIdx.x;                 // 0..191
  int x8 = bid & 7, jj = bid >> 3;      // XCD id, 0..23
  int ct = x8 * 3 + (jj >> 3);          // col tile 0..23 (64 cols each)
  int bx = jj & 7;                      // row tile 0..7 (128 rows each)

  __shared__ u16 lds[2 * 20480];        // 2 x 40 KB: [A 16K | Wr 8K | Wz 8K | Wn 8K]
  char* ldsb = (char*)lds;

  int tid = threadIdx.x, wid = tid >> 6, lane = tid & 63;
  int wm = wid >> 1, wn = wid & 1;      // 4m x 2n wave grid
  int lrow = lane & 15, lkh = lane >> 4;

  for (int t = 0; t < LMAX; ++t) {
    const u16* h_cur = (t & 1) ? hb1 : hb0;
    u16*       h_nxt = (t & 1) ? hb0 : hb1;
    int cnt = counts[t];
    const int* list = lists + t * B_SZ;

    if (bx * 128 < cnt) {
      f32x4 acc[3][2][2] = {};

      auto STAGE = [&](int buf, int kt){
        int k0 = kt * 64;
        char* base = ldsb + buf * 40960;
        #pragma unroll
        for (int it = 0; it < 5; ++it) {
          int cb = it * 512 + wid * 64;
          int c  = cb + lane;
          const u16* src;
          if (c < 1024) {               // A: h rows (gather via active list)
            int row = c >> 3, slot = c & 7;
            int ridx = bx * 128 + row; if (ridx >= cnt) ridx = cnt - 1;
            src = h_cur + (size_t)list[ridx] * H_DIM + k0 + ((slot ^ (row & 7)) << 3);
          } else {                      // W slabs
            int w = c - 1024;
            int slab = w >> 9, row = (w >> 3) & 63, slot = w & 7;
            src = whh_bf + (size_t)(slab * H_DIM + ct * 64 + row) * H_DIM
                  + k0 + ((slot ^ (row & 7)) << 3);
          }
          gload_lds16(src, base + (size_t)cb * 16);
        }
      };

      auto COMPUTE = [&](int buf){
        char* base = ldsb + buf * 40960;
        #pragma unroll
        for (int qq = 0; qq < 2; ++qq) {
          short8 ah[2], bw[3][2];
          int slot = qq * 4 + lkh;
          #pragma unroll
          for (int m = 0; m < 2; ++m) {
            int row = wm * 32 + m * 16 + lrow;
            ah[m] = *(const short8*)(base + row * 128 + ((slot ^ (row & 7)) << 4));
          }
          #pragma unroll
          for (int n = 0; n < 2; ++n) {
            int row = wn * 32 + n * 16 + lrow;
            int byte = row * 128 + ((slot ^ (row & 7)) << 4);
            #pragma unroll
            for (int s = 0; s < 3; ++s)
              bw[s][n] = *(const short8*)(base + 16384 + s * 8192 + byte);
          }
          #pragma unroll
          for (int s = 0; s < 3; ++s)
            #pragma unroll
            for (int m = 0; m < 2; ++m)
              #pragma unroll
              for (int n = 0; n < 2; ++n)
                acc[s][m][n] = __builtin_amdgcn_mfma_f32_16x16x32_bf16(
                    ah[m], bw[s][n], acc[s][m][n], 0, 0, 0);
        }
      };

      STAGE(0, 0);
      __syncthreads();
      int cur = 0;
      for (int kt = 0; kt < 24; ++kt) {
        if (kt + 1 < 24) STAGE(cur ^ 1, kt + 1);
        COMPUTE(cur);
        __syncthreads();
        cur ^= 1;
      }

      // gates
      #pragma unroll
      for (int n = 0; n < 2; ++n) {
        int lc = wn * 32 + n * 16 + lrow;
        int j = ct * 64 + lc;
        float bhr = b_hh[j], bhz = b_hh[H_DIM + j], bhn = b_hh[2*H_DIM + j];
        #pragma unroll
        for (int m = 0; m < 2; ++m)
          #pragma unroll
          for (int r4 = 0; r4 < 4; ++r4) {
            int lm = wm * 32 + m * 16 + lkh * 4 + r4;
            int ridx = bx * 128 + lm;
            if (ridx < cnt) {
              int grow = list[ridx];
              size_t gr = (size_t)(offsets[grow] + t) * 4608;
              float gir = bf2f(gi[gr + j]);
              float giz = bf2f(gi[gr + H_DIM + j]);
              float gin = bf2f(gi[gr + 2*H_DIM + j]);
              float r = sigm(gir + acc[0][m][n][r4] + bhr);
              float z = sigm(giz + acc[1][m][n][r4] + bhz);
              float nn = tanhf(gin + r * (acc[2][m][n][r4] + bhn));
              float hold = bf2f(h_cur[(size_t)grow * H_DIM + j]);
              h_nxt[(size_t)grow * H_DIM + j] = f2bf((1.f - z) * nn + z * hold);
            }
          }
      }
    }

    // ---- grid barrier (skip after last step) ----
    if (t + 1 < LMAX) {
      __threadfence();                  // make h_nxt visible device-wide
      __syncthreads();                  // all waves of block done
      if (tid == 0) {
        __hip_atomic_fetch_add(bar, 1, __ATOMIC_RELEASE, __HIP_MEMORY_SCOPE_AGENT);
        int target = GH_BLOCKS * (t + 1);
        while (__hip_atomic_load(bar, __ATOMIC_ACQUIRE, __HIP_MEMORY_SCOPE_AGENT) < target)
          __builtin_amdgcn_s_sleep(8);
      }
      __syncthreads();                  // release whole block past barrier
    }
  }
}

// ---------------- scores: (h_final/T) @ k^T ----------------
__global__ __launch_bounds__(256, 2) void scores_kernel(
    const u16* __restrict__ h0, const u16* __restrict__ h1,
    const int* __restrict__ lens, const u16* __restrict__ k_bf,
    float* __restrict__ scores)
{
  int bx = blockIdx.x, by = blockIdx.y;
  __shared__ u16 lds[2 * 64 * 64];
  char* ldsb = (char*)lds;
  int tid = threadIdx.x, wid = tid >> 6, lane = tid & 63;
  int wm = wid >> 1, wn = wid & 1;
  int lrow = lane & 15, lkh = lane >> 4;
  f32x4 acc[2][2] = {};

  for (int kt = 0; kt < 24; ++kt) {
    int k0 = kt * 64;
    #pragma unroll
    for (int it = 0; it < 4; ++it) {
      int cb = it * 256 + wid * 64;
      int c  = cb + lane;
      int isB = c >> 9;
      int cc  = c & 511;
      int row = cc >> 3, slot = cc & 7;
      const u16* src;
      if (!isB) {
        int g = bx * 64 + row;
        src = ((lens[g] & 1) ? h1 : h0) + (size_t)g * H_DIM;
      } else {
        src = k_bf + (size_t)(by * 64 + row) * H_DIM;
      }
      src += k0 + ((slot ^ (row & 7)) << 3);
      gload_lds16(src, ldsb + (size_t)cb * 16);
    }
    __syncthreads();
    #pragma unroll
    for (int qq = 0; qq < 2; ++qq) {
      short8 a[2], b[2];
      int slot = qq * 4 + lkh;
      #pragma unroll
      for (int m = 0; m < 2; ++m) {
        int row = wm * 32 + m * 16 + lrow;
        a[m] = *(const short8*)(ldsb + row * 128 + ((slot ^ (row & 7)) << 4));
      }
      #pragma unroll
      for (int n = 0; n < 2; ++n) {
        int row = wn * 32 + n * 16 + lrow;
        b[n] = *(const short8*)(ldsb + 8192 + row * 128 + ((slot ^ (row & 7)) << 4));
      }
      #pragma unroll
      for (int m = 0; m < 2; ++m)
        #pragma unroll
        for (int n = 0; n < 2; ++n)
          acc[m][n] = __builtin_amdgcn_mfma_f32_16x16x32_bf16(a[m], b[n], acc[m][n], 0,0,0);
    }
    __syncthreads();
  }
  #pragma unroll
  for (int m = 0; m < 2; ++m)
    #pragma unroll
    for (int n = 0; n < 2; ++n) {
      int col = by * 64 + wn * 32 + n * 16 + lrow;
      #pragma unroll
      for (int r4 = 0; r4 < 4; ++r4) {
        int rowg = bx * 64 + wm * 32 + m * 16 + lkh * 4 + r4;
        scores[(size_t)rowg * B_SZ + col] = acc[m][n][r4] * TEMP_INV;
      }
    }
}

// ---------------- per-row logsumexp loss ----------------
__global__ void softmax_kernel(const float* __restrict__ scores, float* __restrict__ row_loss){
  int i = blockIdx.x;
  int tid = threadIdx.x;
  const float* row = scores + (size_t)i * B_SZ;
  __shared__ float red[4];
  float m = -INFINITY;
  for (int j = tid; j < B_SZ; j += 256) m = fmaxf(m, row[j]);
  for (int off = 32; off; off >>= 1) m = fmaxf(m, __shfl_xor(m, off));
  if ((tid & 63) == 0) red[tid >> 6] = m;
  __syncthreads();
  m = fmaxf(fmaxf(red[0], red[1]), fmaxf(red[2], red[3]));
  __syncthreads();
  float s = 0.f;
  for (int j = tid; j < B_SZ; j += 256) s += __expf(row[j] - m);
  for (int off = 32; off; off >>= 1) s += __shfl_xor(s, off);
  if ((tid & 63) == 0) red[tid >> 6] = s;
  __syncthreads();
  if (tid == 0) {
    float S = red[0] + red[1] + red[2] + red[3];
    row_loss[i] = m + __logf(S) - row[i];
  }
}

__global__ void final_kernel(const float* __restrict__ row_loss, float* __restrict__ out){
  __shared__ float s[B_SZ];
  int i = threadIdx.x;
  s[i] = row_loss[i]; __syncthreads();
  for (int off = 512; off; off >>= 1) {
    if (i < off) s[i] += s[i + off];
    __syncthreads();
  }
  if (i == 0) out[0] = s[0] * (1.0f / B_SZ);
}

// ---------------- launch ----------------
extern "C" void kernel_launch(void* const* d_in, const int* in_sizes, int n_in,
                              void* d_out, int out_size, void* d_ws, size_t ws_size,
                              hipStream_t stream) {
  const float* q_emb = (const float*)d_in[0];
  const float* k_emb = (const float*)d_in[1];
  const float* inpn  = (const float*)d_in[2];
  const int*   lens  = (const int*)d_in[3];
  const float* wih   = (const float*)d_in[4];
  const float* whh   = (const float*)d_in[5];
  const float* bih   = (const float*)d_in[6];
  const float* bhh   = (const float*)d_in[7];
  float* out = (float*)d_out;

  int total  = in_sizes[2] / H_DIM;
  int mtiles = (total + 127) / 128;
  int Mpad   = mtiles * 128;

  char* p = (char*)d_ws;
  auto alloc = [&](size_t bytes){ char* r = p; p += (bytes + 255) & ~(size_t)255; return r; };
  int* offsets   = (int*)alloc(B_SZ * 4);
  int* counts    = (int*)alloc(LMAX * 4);
  int* bar       = (int*)alloc(256);
  int* lists_    = (int*)alloc((size_t)LMAX * B_SZ * 4);
  u16* hbuf0     = (u16*)alloc((size_t)B_SZ * H_DIM * 2);
  u16* hbuf1     = (u16*)alloc((size_t)B_SZ * H_DIM * 2);
  u16* wih_bf    = (u16*)alloc((size_t)H3 * H_DIM * 2);
  u16* whh_bf    = (u16*)alloc((size_t)H3 * H_DIM * 2);
  u16* k_bf      = (u16*)alloc((size_t)B_SZ * H_DIM * 2);
  u16* x_bf      = (u16*)alloc((size_t)Mpad * H_DIM * 2);
  u16* gi        = (u16*)alloc((size_t)Mpad * H3 * 2);
  float* scores  = (float*)alloc((size_t)B_SZ * B_SZ * 4);
  float* row_loss= (float*)alloc(B_SZ * 4);
  if ((size_t)(p - (char*)d_ws) > ws_size) return;  // workspace too small (loud fail)

  hipMemsetAsync(bar, 0, 256, stream);              // barrier counter must start at 0

  prep_kernel<<<(H3 * H_DIM / 8) / 256, 256, 0, stream>>>(
      wih, whh, k_emb, q_emb, wih_bf, whh_bf, k_bf, hbuf0);
  convx_kernel<<<((size_t)Mpad * H_DIM / 8) / 256, 256, 0, stream>>>(inpn, x_bf, total);
  offsets_kernel<<<1, B_SZ, 0, stream>>>(lens, offsets);
  lists_kernel<<<LMAX, B_SZ, 0, stream>>>(lens, lists_, counts);

  gi_gemm_kernel<<<mtiles * 36, 256, 0, stream>>>(x_bf, wih_bf, bih, gi, mtiles);

  gh_persist_kernel<<<GH_BLOCKS, 512, 0, stream>>>(
      hbuf0, hbuf1, whh_bf, gi, bhh, offsets, lists_, counts, bar);

  scores_kernel<<<dim3(B_SZ / 64, B_SZ / 64), 256, 0, stream>>>(
      hbuf0, hbuf1, lens, k_bf, scores);
  softmax_kernel<<<B_SZ, 256, 0, stream>>>(scores, row_loss);
  final_kernel<<<1, B_SZ, 0, stream>>>(row_loss, out);
}

// Round 5
// 1951.327 us; speedup vs baseline: 2.3390x; 2.3390x over previous
//
#include <hip/hip_runtime.h>
#include <hip/hip_bf16.h>

#define B_SZ 1024
#define H_DIM 1536
#define H3 (3*H_DIM)
#define LMAX 32
#define TEMP_INV 20.0f
#define NCB 48                    // col-blocks (32 h-cols each)
#define NRG 4                     // row groups
#define GH_BLOCKS (NCB*NRG)       // 192
#define GH_THREADS 768

typedef __attribute__((ext_vector_type(4))) float f32x4;
typedef __attribute__((ext_vector_type(8))) short short8;
typedef unsigned short u16;
typedef unsigned int u32;

__device__ __forceinline__ u16 f2bf(float f){
  union { float f; u32 u; } v; v.f = f;
  u32 r = (v.u + 0x7FFFu + ((v.u >> 16) & 1u)) >> 16;
  return (u16)r;
}
__device__ __forceinline__ u32 pack2(float lo, float hi){
  return (u32)f2bf(lo) | ((u32)f2bf(hi) << 16);
}
__device__ __forceinline__ float bf2f(u16 b){
  union { u32 u; float f; } v; v.u = ((u32)b) << 16; return v.f;
}
__device__ __forceinline__ float sigm(float x){ return 1.f / (1.f + __expf(-x)); }

__device__ __forceinline__ void gload_lds16(const void* g, void* l){
  __builtin_amdgcn_global_load_lds(
      (const __attribute__((address_space(1))) void*)g,
      (__attribute__((address_space(3))) void*)l, 16, 0, 0);
}

// ---------------- prep: weights/k -> bf16, h0 = bf16(q) ----------------
__global__ void prep_kernel(const float* __restrict__ wih, const float* __restrict__ whh,
                            const float* __restrict__ kemb, const float* __restrict__ qemb,
                            u16* __restrict__ wih_bf, u16* __restrict__ whh_bf,
                            u16* __restrict__ k_bf, u16* __restrict__ h0)
{
  size_t o = ((size_t)blockIdx.x * 256 + threadIdx.x) * 8;
  if (o < (size_t)H3 * H_DIM) {
    float4 a0 = *(const float4*)(wih + o), a1 = *(const float4*)(wih + o + 4);
    *(uint4*)(wih_bf + o) = make_uint4(pack2(a0.x,a0.y), pack2(a0.z,a0.w),
                                       pack2(a1.x,a1.y), pack2(a1.z,a1.w));
    float4 b0 = *(const float4*)(whh + o), b1 = *(const float4*)(whh + o + 4);
    *(uint4*)(whh_bf + o) = make_uint4(pack2(b0.x,b0.y), pack2(b0.z,b0.w),
                                       pack2(b1.x,b1.y), pack2(b1.z,b1.w));
  }
  if (o < (size_t)B_SZ * H_DIM) {
    float4 k0 = *(const float4*)(kemb + o), k1 = *(const float4*)(kemb + o + 4);
    *(uint4*)(k_bf + o) = make_uint4(pack2(k0.x,k0.y), pack2(k0.z,k0.w),
                                     pack2(k1.x,k1.y), pack2(k1.z,k1.w));
    float4 q0 = *(const float4*)(qemb + o), q1 = *(const float4*)(qemb + o + 4);
    *(uint4*)(h0 + o) = make_uint4(pack2(q0.x,q0.y), pack2(q0.z,q0.w),
                                   pack2(q1.x,q1.y), pack2(q1.z,q1.w));
  }
}

// ---------------- convert inpn f32 -> bf16 (zero-pad to Mpad) ----------------
__global__ void convx_kernel(const float* __restrict__ x, u16* __restrict__ x_bf, int total){
  size_t o = ((size_t)blockIdx.x * 256 + threadIdx.x) * 8;
  int row = (int)(o / H_DIM);
  uint4 v;
  if (row < total) {
    float4 a0 = *(const float4*)(x + o), a1 = *(const float4*)(x + o + 4);
    v = make_uint4(pack2(a0.x,a0.y), pack2(a0.z,a0.w), pack2(a1.x,a1.y), pack2(a1.z,a1.w));
  } else v = make_uint4(0,0,0,0);
  *(uint4*)(x_bf + o) = v;
}

// ---------------- offsets: exclusive cumsum of lens ----------------
__global__ void offsets_kernel(const int* __restrict__ lens, int* __restrict__ offsets){
  __shared__ int s[B_SZ];
  int i = threadIdx.x;
  int v = lens[i];
  s[i] = v; __syncthreads();
  for (int off = 1; off < B_SZ; off <<= 1){
    int t = (i >= off) ? s[i-off] : 0;
    __syncthreads();
    s[i] += t;
    __syncthreads();
  }
  offsets[i] = s[i] - v;
}

// ---------------- active-row lists per step ----------------
__global__ void lists_kernel(const int* __restrict__ lens, int* __restrict__ lists,
                             int* __restrict__ counts){
  int t = blockIdx.x;
  int i = threadIdx.x;
  __shared__ int s[B_SZ];
  int f = (lens[i] > t) ? 1 : 0;
  s[i] = f; __syncthreads();
  for (int off = 1; off < B_SZ; off <<= 1){
    int v = (i >= off) ? s[i-off] : 0;
    __syncthreads();
    s[i] += v;
    __syncthreads();
  }
  if (f) lists[t*B_SZ + s[i] - 1] = i;
  if (i == B_SZ-1) counts[t] = s[B_SZ-1];
}

// ---------------- GI = x_bf @ W_ih^T + b_ih  (128x128 tile, BK=64) ----------------
__global__ __launch_bounds__(256, 2) void gi_gemm_kernel(
    const u16* __restrict__ x_bf, const u16* __restrict__ wih_bf,
    const float* __restrict__ b_ih, u16* __restrict__ gi, int nblk_m)
{
  int nblk = nblk_m * 36;
  int id = blockIdx.x;
  int q8 = nblk >> 3, r8 = nblk & 7;
  int xcd = id & 7, off = id >> 3;
  int swz = (xcd < r8) ? (xcd * (q8 + 1) + off) : (r8 * (q8 + 1) + (xcd - r8) * q8 + off);
  int bx = swz / 36, by = swz % 36;

  __shared__ u16 lds[2 * 128 * 64];   // 32 KB: A then B
  char* ldsb = (char*)lds;
  int tid = threadIdx.x, wid = tid >> 6, lane = tid & 63;
  int wm = wid >> 1, wn = wid & 1;
  int lrow = lane & 15, lkh = lane >> 4;
  f32x4 acc[4][4] = {};

  for (int kt = 0; kt < 24; ++kt) {
    int k0 = kt * 64;
    #pragma unroll
    for (int it = 0; it < 8; ++it) {
      int cb = it * 256 + wid * 64;        // wave-uniform chunk base
      int c  = cb + lane;
      int isB = c >> 10;
      int cc  = c & 1023;
      int row = cc >> 3, slot = cc & 7;
      const u16* src = isB ? (wih_bf + (size_t)(by * 128 + row) * H_DIM)
                           : (x_bf  + (size_t)(bx * 128 + row) * H_DIM);
      src += k0 + ((slot ^ (row & 7)) << 3);
      gload_lds16(src, ldsb + (size_t)cb * 16);
    }
    __syncthreads();
    #pragma unroll
    for (int qq = 0; qq < 2; ++qq) {
      short8 a[4], b[4];
      int slot = qq * 4 + lkh;
      #pragma unroll
      for (int m = 0; m < 4; ++m) {
        int row = wm * 64 + m * 16 + lrow;
        a[m] = *(const short8*)(ldsb + row * 128 + ((slot ^ (row & 7)) << 4));
      }
      #pragma unroll
      for (int n = 0; n < 4; ++n) {
        int row = wn * 64 + n * 16 + lrow;
        b[n] = *(const short8*)(ldsb + 16384 + row * 128 + ((slot ^ (row & 7)) << 4));
      }
      #pragma unroll
      for (int m = 0; m < 4; ++m)
        #pragma unroll
        for (int n = 0; n < 4; ++n)
          acc[m][n] = __builtin_amdgcn_mfma_f32_16x16x32_bf16(a[m], b[n], acc[m][n], 0,0,0);
    }
    __syncthreads();
  }
  #pragma unroll
  for (int n = 0; n < 4; ++n) {
    int j = by * 128 + wn * 64 + n * 16 + lrow;
    float bias = b_ih[j];
    #pragma unroll
    for (int m = 0; m < 4; ++m)
      #pragma unroll
      for (int r4 = 0; r4 < 4; ++r4) {
        int rowg = bx * 128 + wm * 64 + m * 16 + lkh * 4 + r4;
        gi[(size_t)rowg * 4608 + j] = f2bf(acc[m][n][r4] + bias);
      }
  }
}

// ---------------- persistent GRU recurrence, W_hh held in registers ----------
// 192 blocks = 48 col-blocks (32 h-cols) x 4 row-groups; 768 thr = 12 waves
// = 3 slabs x 2 strips x 2 K-halves. Each wave: 24 W B-frags in VGPRs (96),
// loaded ONCE. Per step: stage h-tile to LDS (swizzled), MFMA vs in-reg W,
// cross-wave LDS reduce, gates, grid barrier (relaxed spin + one acquire).
__global__ __launch_bounds__(GH_THREADS, 3) void gh_persist_kernel(
    u16* __restrict__ hb0, u16* __restrict__ hb1,
    const u16* __restrict__ whh_bf, const u16* __restrict__ gi,
    const float* __restrict__ b_hh,
    const int* __restrict__ offsets, const int* __restrict__ lists,
    const int* __restrict__ counts, int* __restrict__ bar)
{
  int bid = blockIdx.x;
  int cb = bid % NCB, rg = bid / NCB;
  int tid = threadIdx.x, wid = tid >> 6, lane = tid & 63;
  int s  = wid >> 2;          // slab 0..2
  int p  = (wid >> 1) & 1;    // 16-col strip 0..1
  int kh = wid & 1;           // K half 0..1
  int l15 = lane & 15, l4 = lane >> 4;

  __shared__ char Albuf[2][2][64][256];   // 64 KB: [buf][khalf][row][128 bf16]
  __shared__ float red[3][2][64][32];     // 48 KB gate partials

  // ---- load this wave's W_hh B-fragments once (stay in VGPRs) ----
  short8 wfrag[24];
  {
    const u16* wrow = whh_bf + (size_t)(s * H_DIM + cb * 32 + p * 16 + l15) * H_DIM
                      + kh * 768 + l4 * 8;
    #pragma unroll
    for (int kk = 0; kk < 24; ++kk)
      wfrag[kk] = *(const short8*)(wrow + kk * 32);
  }

  for (int t = 0; t < LMAX; ++t) {
    const u16* h_cur = (t & 1) ? hb1 : hb0;
    u16*       h_nxt = (t & 1) ? hb0 : hb1;
    int cnt = counts[t];
    const int* list = lists + t * B_SZ;

    int qrows = (cnt + NRG - 1) / NRG;
    int rstart = rg * qrows;
    int rend = min(rstart + qrows, cnt);

    for (int rbase = rstart; rbase < rend; rbase += 64) {
      // ---- stage: 64 rows x full K (both halves), pre-swizzled source ----
      auto STAGE = [&](int buf, int ch){
        #pragma unroll
        for (int it = 0; it < 3; ++it) {
          int c = it * 768 + tid;          // 16B chunk id, 2048 total
          if (c < 2048) {                  // boundary is wave-uniform (2048%64==0)
            int khp = c >> 10, cc = c & 1023, row = cc >> 4, slot = cc & 15;
            int pos = rbase + row; if (pos >= cnt) pos = cnt - 1;
            const u16* src = h_cur + (size_t)list[pos] * H_DIM
                             + khp * 768 + ch * 128 + ((slot ^ (row & 15)) << 3);
            gload_lds16(src, &Albuf[buf][khp][row][slot * 16]);
          }
        }
      };

      f32x4 acc[4] = {};
      STAGE(0, 0);
      __syncthreads();
      #pragma unroll
      for (int ch = 0; ch < 6; ++ch) {     // 6 chunks x 128 K per half
        if (ch < 5) STAGE((ch + 1) & 1, ch + 1);
        #pragma unroll
        for (int kkl = 0; kkl < 4; ++kkl) {
          #pragma unroll
          for (int rf = 0; rf < 4; ++rf) {
            int row = rf * 16 + l15;
            short8 a = *(const short8*)(&Albuf[ch & 1][kh][row]
                                        [((kkl * 4 + l4) ^ (row & 15)) * 16]);
            acc[rf] = __builtin_amdgcn_mfma_f32_16x16x32_bf16(
                a, wfrag[ch * 4 + kkl], acc[rf], 0, 0, 0);
          }
        }
        __syncthreads();
      }

      // ---- cross-wave reduce: write partials ----
      #pragma unroll
      for (int rf = 0; rf < 4; ++rf) {
        int row = rf * 16 + l4 * 4;
        #pragma unroll
        for (int r = 0; r < 4; ++r)
          red[s][kh][row + r][p * 16 + l15] = acc[rf][r];
      }
      __syncthreads();

      // ---- gates ----
      int rcount = rend - rbase; if (rcount > 64) rcount = 64;
      for (int o = tid; o < 64 * 32; o += GH_THREADS) {
        int r = o >> 5, c = o & 31;
        if (r < rcount) {
          int grow = list[rbase + r];
          float ghr = red[0][0][r][c] + red[0][1][r][c];
          float ghz = red[1][0][r][c] + red[1][1][r][c];
          float ghn = red[2][0][r][c] + red[2][1][r][c];
          int j = cb * 32 + c;
          size_t gb = (size_t)(offsets[grow] + t) * 4608 + j;
          float rr = sigm(bf2f(gi[gb])        + ghr + b_hh[j]);
          float zz = sigm(bf2f(gi[gb + 1536]) + ghz + b_hh[H_DIM + j]);
          float nn = tanhf(bf2f(gi[gb + 3072]) + rr * (ghn + b_hh[2 * H_DIM + j]));
          float hold = bf2f(h_cur[(size_t)grow * H_DIM + j]);
          h_nxt[(size_t)grow * H_DIM + j] = f2bf((1.f - zz) * nn + zz * hold);
        }
      }
      __syncthreads();                     // red/Albuf reused next round
    }

    // ---- grid barrier: release add, RELAXED spin, one acquire fence ----
    if (t + 1 < LMAX) {
      __syncthreads();
      if (tid == 0) {
        __hip_atomic_fetch_add(bar, 1, __ATOMIC_RELEASE, __HIP_MEMORY_SCOPE_AGENT);
        int target = GH_BLOCKS * (t + 1);
        int guard = 0;
        while (__hip_atomic_load(bar, __ATOMIC_RELAXED, __HIP_MEMORY_SCOPE_AGENT) < target
               && ++guard < 100000000)
          __builtin_amdgcn_s_sleep(2);
      }
      __syncthreads();
      __builtin_amdgcn_fence(__ATOMIC_ACQUIRE, "agent");  // one L2 inv per step
    }
  }
}

// ---------------- scores: (h_final/T) @ k^T ----------------
__global__ __launch_bounds__(256, 2) void scores_kernel(
    const u16* __restrict__ h0, const u16* __restrict__ h1,
    const int* __restrict__ lens, const u16* __restrict__ k_bf,
    float* __restrict__ scores)
{
  int bx = blockIdx.x, by = blockIdx.y;
  __shared__ u16 lds[2 * 64 * 64];
  char* ldsb = (char*)lds;
  int tid = threadIdx.x, wid = tid >> 6, lane = tid & 63;
  int wm = wid >> 1, wn = wid & 1;
  int lrow = lane & 15, lkh = lane >> 4;
  f32x4 acc[2][2] = {};

  for (int kt = 0; kt < 24; ++kt) {
    int k0 = kt * 64;
    #pragma unroll
    for (int it = 0; it < 4; ++it) {
      int cb = it * 256 + wid * 64;
      int c  = cb + lane;
      int isB = c >> 9;
      int cc  = c & 511;
      int row = cc >> 3, slot = cc & 7;
      const u16* src;
      if (!isB) {
        int g = bx * 64 + row;
        src = ((lens[g] & 1) ? h1 : h0) + (size_t)g * H_DIM;
      } else {
        src = k_bf + (size_t)(by * 64 + row) * H_DIM;
      }
      src += k0 + ((slot ^ (row & 7)) << 3);
      gload_lds16(src, ldsb + (size_t)cb * 16);
    }
    __syncthreads();
    #pragma unroll
    for (int qq = 0; qq < 2; ++qq) {
      short8 a[2], b[2];
      int slot = qq * 4 + lkh;
      #pragma unroll
      for (int m = 0; m < 2; ++m) {
        int row = wm * 32 + m * 16 + lrow;
        a[m] = *(const short8*)(ldsb + row * 128 + ((slot ^ (row & 7)) << 4));
      }
      #pragma unroll
      for (int n = 0; n < 2; ++n) {
        int row = wn * 32 + n * 16 + lrow;
        b[n] = *(const short8*)(ldsb + 8192 + row * 128 + ((slot ^ (row & 7)) << 4));
      }
      #pragma unroll
      for (int m = 0; m < 2; ++m)
        #pragma unroll
        for (int n = 0; n < 2; ++n)
          acc[m][n] = __builtin_amdgcn_mfma_f32_16x16x32_bf16(a[m], b[n], acc[m][n], 0,0,0);
    }
    __syncthreads();
  }
  #pragma unroll
  for (int m = 0; m < 2; ++m)
    #pragma unroll
    for (int n = 0; n < 2; ++n) {
      int col = by * 64 + wn * 32 + n * 16 + lrow;
      #pragma unroll
      for (int r4 = 0; r4 < 4; ++r4) {
        int rowg = bx * 64 + wm * 32 + m * 16 + lkh * 4 + r4;
        scores[(size_t)rowg * B_SZ + col] = acc[m][n][r4] * TEMP_INV;
      }
    }
}

// ---------------- per-row logsumexp loss ----------------
__global__ void softmax_kernel(const float* __restrict__ scores, float* __restrict__ row_loss){
  int i = blockIdx.x;
  int tid = threadIdx.x;
  const float* row = scores + (size_t)i * B_SZ;
  __shared__ float red[4];
  float m = -INFINITY;
  for (int j = tid; j < B_SZ; j += 256) m = fmaxf(m, row[j]);
  for (int off = 32; off; off >>= 1) m = fmaxf(m, __shfl_xor(m, off));
  if ((tid & 63) == 0) red[tid >> 6] = m;
  __syncthreads();
  m = fmaxf(fmaxf(red[0], red[1]), fmaxf(red[2], red[3]));
  __syncthreads();
  float s = 0.f;
  for (int j = tid; j < B_SZ; j += 256) s += __expf(row[j] - m);
  for (int off = 32; off; off >>= 1) s += __shfl_xor(s, off);
  if ((tid & 63) == 0) red[tid >> 6] = s;
  __syncthreads();
  if (tid == 0) {
    float S = red[0] + red[1] + red[2] + red[3];
    row_loss[i] = m + __logf(S) - row[i];
  }
}

__global__ void final_kernel(const float* __restrict__ row_loss, float* __restrict__ out){
  __shared__ float s[B_SZ];
  int i = threadIdx.x;
  s[i] = row_loss[i]; __syncthreads();
  for (int off = 512; off; off >>= 1) {
    if (i < off) s[i] += s[i + off];
    __syncthreads();
  }
  if (i == 0) out[0] = s[0] * (1.0f / B_SZ);
}

// ---------------- launch ----------------
extern "C" void kernel_launch(void* const* d_in, const int* in_sizes, int n_in,
                              void* d_out, int out_size, void* d_ws, size_t ws_size,
                              hipStream_t stream) {
  const float* q_emb = (const float*)d_in[0];
  const float* k_emb = (const float*)d_in[1];
  const float* inpn  = (const float*)d_in[2];
  const int*   lens  = (const int*)d_in[3];
  const float* wih   = (const float*)d_in[4];
  const float* whh   = (const float*)d_in[5];
  const float* bih   = (const float*)d_in[6];
  const float* bhh   = (const float*)d_in[7];
  float* out = (float*)d_out;

  int total  = in_sizes[2] / H_DIM;
  int mtiles = (total + 127) / 128;
  int Mpad   = mtiles * 128;

  char* p = (char*)d_ws;
  auto alloc = [&](size_t bytes){ char* r = p; p += (bytes + 255) & ~(size_t)255; return r; };
  int* offsets   = (int*)alloc(B_SZ * 4);
  int* counts    = (int*)alloc(LMAX * 4);
  int* bar       = (int*)alloc(256);
  int* lists_    = (int*)alloc((size_t)LMAX * B_SZ * 4);
  u16* hbuf0     = (u16*)alloc((size_t)B_SZ * H_DIM * 2);
  u16* hbuf1     = (u16*)alloc((size_t)B_SZ * H_DIM * 2);
  u16* wih_bf    = (u16*)alloc((size_t)H3 * H_DIM * 2);
  u16* whh_bf    = (u16*)alloc((size_t)H3 * H_DIM * 2);
  u16* k_bf      = (u16*)alloc((size_t)B_SZ * H_DIM * 2);
  u16* x_bf      = (u16*)alloc((size_t)Mpad * H_DIM * 2);
  u16* gi        = (u16*)alloc((size_t)Mpad * H3 * 2);
  float* scores  = (float*)alloc((size_t)B_SZ * B_SZ * 4);
  float* row_loss= (float*)alloc(B_SZ * 4);
  if ((size_t)(p - (char*)d_ws) > ws_size) return;  // workspace too small (loud fail)

  hipMemsetAsync(bar, 0, 256, stream);              // barrier counter must start at 0

  prep_kernel<<<(H3 * H_DIM / 8) / 256, 256, 0, stream>>>(
      wih, whh, k_emb, q_emb, wih_bf, whh_bf, k_bf, hbuf0);
  convx_kernel<<<((size_t)Mpad * H_DIM / 8) / 256, 256, 0, stream>>>(inpn, x_bf, total);
  offsets_kernel<<<1, B_SZ, 0, stream>>>(lens, offsets);
  lists_kernel<<<LMAX, B_SZ, 0, stream>>>(lens, lists_, counts);

  gi_gemm_kernel<<<mtiles * 36, 256, 0, stream>>>(x_bf, wih_bf, bih, gi, mtiles);

  gh_persist_kernel<<<GH_BLOCKS, GH_THREADS, 0, stream>>>(
      hbuf0, hbuf1, whh_bf, gi, bhh, offsets, lists_, counts, bar);

  scores_kernel<<<dim3(B_SZ / 64, B_SZ / 64), 256, 0, stream>>>(
      hbuf0, hbuf1, lens, k_bf, scores);
  softmax_kernel<<<B_SZ, 256, 0, stream>>>(scores, row_loss);
  final_kernel<<<1, B_SZ, 0, stream>>>(row_loss, out);
}